// Round 1
// baseline (413.166 us; speedup 1.0000x reference)
//
#include <hip/hip_runtime.h>

#define KCODES 512
#define DIM    64
#define HWPB   256   // H*W pixels per batch image = pixels per block

// --- prep: per-code squared norms ---------------------------------------
__global__ __launch_bounds__(256) void vq_prep(const float* __restrict__ e,
                                               float* __restrict__ enorm) {
    int j = blockIdx.x * blockDim.x + threadIdx.x;
    if (j < KCODES) {
        const float* er = e + j * DIM;
        float s = 0.f;
        #pragma unroll
        for (int d = 0; d < DIM; ++d) s = fmaf(er[d], er[d], s);
        enorm[j] = s;
    }
}

// --- main: one thread per pixel; e streamed via scalar (wave-uniform) loads
__global__ __launch_bounds__(256, 4) void vq_main(
        const float* __restrict__ z, const float* __restrict__ e,
        const float* __restrict__ enorm, float* __restrict__ zq,
        float* __restrict__ counts)
{
    __shared__ int hist[KCODES];
    const int b  = blockIdx.x;
    const int hw = threadIdx.x;          // 0..255, this thread's pixel

    hist[hw]       = 0;
    hist[hw + 256] = 0;

    // Load this pixel's z vector into registers (coalesced across lanes per d).
    const float* zb = z + (size_t)b * (DIM * HWPB) + hw;
    float zr[DIM];
    #pragma unroll
    for (int d = 0; d < DIM; ++d) zr[d] = zb[(size_t)d * HWPB];

    float bestv = 3.4e38f;
    int   besti = 0;

    // dist = ||z||^2 + ||e_j||^2 - 2 z.e_j ; drop the per-pixel ||z||^2
    // (monotone). Strict < with ascending j == numpy first-min tie-break.
    #pragma unroll 2
    for (int j = 0; j < KCODES; ++j) {
        const float* __restrict__ er = e + j * DIM;   // wave-uniform address
        float a0 = 0.f, a1 = 0.f, a2 = 0.f, a3 = 0.f;
        #pragma unroll
        for (int d = 0; d < DIM; d += 4) {
            a0 = fmaf(zr[d + 0], er[d + 0], a0);
            a1 = fmaf(zr[d + 1], er[d + 1], a1);
            a2 = fmaf(zr[d + 2], er[d + 2], a2);
            a3 = fmaf(zr[d + 3], er[d + 3], a3);
        }
        float dot = (a0 + a1) + (a2 + a3);
        float s = fmaf(-2.f, dot, enorm[j]);
        if (s < bestv) { bestv = s; besti = j; }
    }

    __syncthreads();                 // hist init complete everywhere
    atomicAdd(&hist[besti], 1);

    // Gather the winning code row into z_q (stores coalesced across lanes).
    const float4* er4 = (const float4*)(e + besti * DIM);
    float* ob = zq + (size_t)b * (DIM * HWPB) + hw;
    #pragma unroll
    for (int i = 0; i < DIM / 4; ++i) {
        float4 v = er4[i];
        ob[(size_t)(4 * i + 0) * HWPB] = v.x;
        ob[(size_t)(4 * i + 1) * HWPB] = v.y;
        ob[(size_t)(4 * i + 2) * HWPB] = v.z;
        ob[(size_t)(4 * i + 3) * HWPB] = v.w;
    }

    __syncthreads();                 // all atomics into hist done
    int h0 = hist[hw];        if (h0) atomicAdd(&counts[hw],       (float)h0);
    int h1 = hist[hw + 256];  if (h1) atomicAdd(&counts[hw + 256], (float)h1);
}

// --- epilogue: EMA count update ------------------------------------------
__global__ __launch_bounds__(256) void vq_nupd(const float* __restrict__ N,
        const float* __restrict__ counts, float* __restrict__ outN) {
    int j = blockIdx.x * blockDim.x + threadIdx.x;
    if (j < KCODES) outN[j] = 0.995f * N[j] + 0.005f * counts[j];
}

extern "C" void kernel_launch(void* const* d_in, const int* in_sizes, int n_in,
                              void* d_out, int out_size, void* d_ws, size_t ws_size,
                              hipStream_t stream) {
    const float* z = (const float*)d_in[0];
    const float* e = (const float*)d_in[1];
    const float* N = (const float*)d_in[2];
    float* out = (float*)d_out;
    const int nz = in_sizes[0];               // B*D*H*W = 16777216
    const int B  = nz / (DIM * HWPB);         // 1024

    float* enorm  = (float*)d_ws;             // KCODES floats
    float* counts = enorm + KCODES;           // KCODES floats (ws is 0xAA-poisoned)

    hipMemsetAsync(counts, 0, KCODES * sizeof(float), stream);
    vq_prep<<<(KCODES + 255) / 256, 256, 0, stream>>>(e, enorm);
    vq_main<<<B, 256, 0, stream>>>(z, e, enorm, out, counts);
    vq_nupd<<<(KCODES + 255) / 256, 256, 0, stream>>>(N, counts, out + nz);
}